// Round 8
// baseline (261.916 us; speedup 1.0000x reference)
//
#include <hip/hip_runtime.h>

typedef _Float16 half8 __attribute__((ext_vector_type(8)));
typedef _Float16 half4v __attribute__((ext_vector_type(4)));
typedef _Float16 half2v __attribute__((ext_vector_type(2)));
typedef float floatx4 __attribute__((ext_vector_type(4)));

#define AS3 __attribute__((address_space(3)))
#define AS1 __attribute__((address_space(1)))

// ---------------- fused f32 -> f16 convert of all three inputs ----------------
__global__ __launch_bounds__(256) void cvt_all(const float* __restrict__ x,
                                               const float* __restrict__ wq,
                                               const float* __restrict__ wp,
                                               _Float16* __restrict__ xh,
                                               _Float16* __restrict__ wqh,
                                               _Float16* __restrict__ wph) {
    long i = (long)blockIdx.x * 256 + threadIdx.x;   // float4 index
    const float4* src; half4v* dst; long off;
    if (i < 2097152)      { src = (const float4*)x;  dst = (half4v*)xh;  off = i; }
    else if (i < 2883584) { src = (const float4*)wq; dst = (half4v*)wqh; off = i - 2097152; }
    else                  { src = (const float4*)wp; dst = (half4v*)wph; off = i - 2883584; }
    float4 v = src[off];
    half4v h = {(_Float16)v.x, (_Float16)v.y, (_Float16)v.z, (_Float16)v.w};
    dst[off] = h;
}

// ---------------- TN GEMM, global->VGPR->LDS pipeline, XOR-swizzled ----------
// C[M,N] = A[M,K] * B[N,K]^T. 128x128 tile, BK=32, 256 threads, dbuf LDS.
// Columns >= split are written TRANSPOSED into Vt[bh*64+d][n] (8B half4
// stores; m-rows are consecutive n there).
__global__ __launch_bounds__(256, 4) void gemm_tn(
    const _Float16* __restrict__ A, const _Float16* __restrict__ B,
    _Float16* __restrict__ Ch, int ldc, _Float16* __restrict__ Vt, int split,
    float* __restrict__ Cf, const float* __restrict__ bias,
    int M, int Nn, int K)
{
    __shared__ _Float16 sA[2][128 * 32];
    __shared__ _Float16 sB[2][128 * 32];
    const int tid  = threadIdx.x;
    const int lane = tid & 63, wave = tid >> 6;
    const int quad = lane >> 4, l16 = lane & 15;
    const int wr = wave >> 1, wc = wave & 1;
    const long m0 = (long)blockIdx.x * 128, n0 = (long)blockIdx.y * 128;

    // LDS placement: chunk c of row r -> slot c ^ ((r>>1)&3) (involution;
    // bank-uniform fragment reads, verified R3: SQ_LDS_BANK_CONFLICT = 0).
    const int srow = tid >> 2;
    const int sslot = ((tid & 3) ^ ((srow >> 1) & 3)) * 8;
    const int dlo = srow * 32 + sslot;
    const int dhi = (srow + 64) * 32 + sslot;
    const _Float16* gA0 = A + (m0 + srow) * (long)K + (tid & 3) * 8;
    const _Float16* gA1 = A + (m0 + srow + 64) * (long)K + (tid & 3) * 8;
    const _Float16* gB0 = B + (n0 + srow) * (long)K + (tid & 3) * 8;
    const _Float16* gB1 = B + (n0 + srow + 64) * (long)K + (tid & 3) * 8;

    const int swz = (l16 >> 1) & 3;
    const int aoff = ((quad ^ swz) * 8);

    floatx4 acc[4][4] = {};
    const int nk = K >> 5;

    half8 rA0 = *(const half8*)gA0, rA1 = *(const half8*)gA1;
    half8 rB0 = *(const half8*)gB0, rB1 = *(const half8*)gB1;
    *(half8*)&sA[0][dlo] = rA0; *(half8*)&sA[0][dhi] = rA1;
    *(half8*)&sB[0][dlo] = rB0; *(half8*)&sB[0][dhi] = rB1;

    for (int kk = 0; kk < nk; kk++) {
        const int cur = kk & 1;
        __syncthreads();               // lgkm drain only; vmcnt already 0 here
        const bool more = (kk + 1 < nk);
        if (more) {
            const long k0 = (long)(kk + 1) << 5;
            rA0 = *(const half8*)(gA0 + k0); rA1 = *(const half8*)(gA1 + k0);
            rB0 = *(const half8*)(gB0 + k0); rB1 = *(const half8*)(gB1 + k0);
        }

        const _Float16* cA = &sA[cur][0];
        const _Float16* cB = &sB[cur][0];
        half8 af[4], bf[4];
#pragma unroll
        for (int t = 0; t < 4; t++)
            af[t] = *(const half8*)&cA[(wr * 64 + t * 16 + l16) * 32 + aoff];
#pragma unroll
        for (int t = 0; t < 4; t++)
            bf[t] = *(const half8*)&cB[(wc * 64 + t * 16 + l16) * 32 + aoff];
#pragma unroll
        for (int tm = 0; tm < 4; tm++)
#pragma unroll
            for (int tn = 0; tn < 4; tn++)
                acc[tm][tn] = __builtin_amdgcn_mfma_f32_16x16x32_f16(af[tm], bf[tn], acc[tm][tn], 0, 0, 0);

        if (more) {
            _Float16* nA = &sA[cur ^ 1][0];
            _Float16* nB = &sB[cur ^ 1][0];
            *(half8*)&nA[dlo] = rA0; *(half8*)&nA[dhi] = rA1;   // vmcnt wait lands here,
            *(half8*)&nB[dlo] = rB0; *(half8*)&nB[dhi] = rB1;   // one compute phase after issue
        }
    }

    // epilogue: C/D layout col=lane&15, row=quad*4+reg (verified m89/m91)
#pragma unroll
    for (int tm = 0; tm < 4; tm++) {
        long row = m0 + wr * 64 + tm * 16 + quad * 4;
#pragma unroll
        for (int tn = 0; tn < 4; tn++) {
            long col = n0 + wc * 64 + tn * 16 + l16;
            if (Cf) {
                float bv = bias ? bias[col] : 0.f;
#pragma unroll
                for (int r = 0; r < 4; r++)
                    Cf[(row + r) * (long)Nn + col] = acc[tm][tn][r] + bv;
            } else if (col >= split) {
                long cv = col - split;
                long vrow = ((row >> 10) * 16 + (cv >> 6)) * 64 + (cv & 63);
                long nn = row & 1023;
                half4v pv = {(_Float16)acc[tm][tn][0], (_Float16)acc[tm][tn][1],
                             (_Float16)acc[tm][tn][2], (_Float16)acc[tm][tn][3]};
                *(half4v*)&Vt[vrow * 1024 + nn] = pv;
            } else {
#pragma unroll
                for (int r = 0; r < 4; r++)
                    Ch[(row + r) * (long)ldc + col] = (_Float16)acc[tm][tn][r];
            }
        }
    }
}

// ---------------- flash attention (S^T orientation, log2-domain softmax) -----
// Q fragments pre-scaled by CSC*log2e so MFMA yields log2-domain scores;
// softmax uses exp2f (v_exp_f32 directly, no ln2 mul). K/V staging uses the
// R5 VGPR-prefetch pipeline: loads for tile kt+1 issue after the stage
// barrier; their vmcnt wait lands at the NEXT iteration's ds_write, a full
// compute phase later.
#define QSC 0.18033688f   // 0.125 * log2(e)
__global__ __launch_bounds__(256, 3) void flash_attn(const _Float16* __restrict__ qk,
                                                     const _Float16* __restrict__ vt,
                                                     _Float16* __restrict__ out)
{
    const int bh = blockIdx.x, b = bh >> 4, h = bh & 15;
    const int n0 = blockIdx.y * 128;
    const int tid = threadIdx.x, lane = tid & 63, wave = tid >> 6;
    const int quad = lane >> 4, l16 = lane & 15;

    __shared__ _Float16 sK[64 * 72];        // [kr][d] pad 72
    __shared__ _Float16 sVT[64 * 72];       // [d][kr] pad 72
    __shared__ _Float16 sPT[4][32 * 72];    // per-wave P^T round-trip [q][kr], reused as sOut

    half8 qf[2][2];
    const _Float16 qs = (_Float16)QSC;
    const _Float16* qbase = qk + (long)(b * 1024 + n0 + wave * 32) * 2048 + h * 64;
#pragma unroll
    for (int t = 0; t < 2; t++)
#pragma unroll
        for (int s = 0; s < 2; s++) {
            half8 v = *(const half8*)(qbase + (long)(t * 16 + l16) * 2048 + s * 32 + quad * 8);
#pragma unroll
            for (int j = 0; j < 8; j++) v[j] *= qs;
            qf[t][s] = v;
        }

    const int srow = tid >> 3, scol8 = (tid & 7) * 8;
    const _Float16* kgb = qk + 1024 + h * 64 + scol8 + (long)(b * 1024 + srow) * 2048;
    const _Float16* vgb = vt + (long)(bh * 64 + srow) * 1024 + scol8;

    float m_[2] = {-1e30f, -1e30f}, l_[2] = {0.f, 0.f};
    floatx4 o[2][4] = {};

    // prologue: tile 0 -> regs
    half8 kreg[2], vreg[2];
#pragma unroll
    for (int i = 0; i < 2; i++) {
        kreg[i] = *(const half8*)(kgb + (long)(i * 32) * 2048);
        vreg[i] = *(const half8*)(vgb + (long)(i * 32) * 1024);
    }

    for (int kt = 0; kt < 16; kt++) {
        __syncthreads();    // prev tile's LDS reads done
#pragma unroll
        for (int i = 0; i < 2; i++) {
            *(half8*)&sK[(srow + i * 32) * 72 + scol8]  = kreg[i];   // vmcnt wait here:
            *(half8*)&sVT[(srow + i * 32) * 72 + scol8] = vreg[i];   // issued one compute phase ago
        }
        __syncthreads();    // stage visible
        if (kt + 1 < 16) {
            const int kr1 = (kt + 1) * 64;
#pragma unroll
            for (int i = 0; i < 2; i++) {
                kreg[i] = *(const half8*)(kgb + (long)(kr1 + i * 32) * 2048);
                vreg[i] = *(const half8*)(vgb + (long)(i * 32) * 1024 + kr1);
            }
        }

        // S^T = K Q^T (log2-domain): kr=c*16+quad*4+r, q=t*16+l16
        floatx4 sacc[2][4] = {};
#pragma unroll
        for (int c = 0; c < 4; c++)
#pragma unroll
            for (int s = 0; s < 2; s++) {
                half8 kf = *(const half8*)&sK[(c * 16 + l16) * 72 + s * 32 + quad * 8];
                sacc[0][c] = __builtin_amdgcn_mfma_f32_16x16x32_f16(kf, qf[0][s], sacc[0][c], 0, 0, 0);
                sacc[1][c] = __builtin_amdgcn_mfma_f32_16x16x32_f16(kf, qf[1][s], sacc[1][c], 0, 0, 0);
            }

        // online softmax over kr (log2 domain): in-lane reduce + xor16/xor32
#pragma unroll
        for (int t = 0; t < 2; t++) {
            float mx = -1e30f;
#pragma unroll
            for (int c = 0; c < 4; c++)
#pragma unroll
                for (int r = 0; r < 4; r++) mx = fmaxf(mx, sacc[t][c][r]);
            mx = fmaxf(mx, __shfl_xor(mx, 16));
            mx = fmaxf(mx, __shfl_xor(mx, 32));
            float mn = fmaxf(m_[t], mx);
            float al = exp2f(m_[t] - mn);
            m_[t] = mn;
            float rs = 0.f;
#pragma unroll
            for (int c = 0; c < 4; c++)
#pragma unroll
                for (int r = 0; r < 4; r++) {
                    float p = exp2f(sacc[t][c][r] - mn);
                    sacc[t][c][r] = p;
                    rs += p;
                }
            rs += __shfl_xor(rs, 16);
            rs += __shfl_xor(rs, 32);
            l_[t] = l_[t] * al + rs;
#pragma unroll
            for (int dt = 0; dt < 4; dt++) o[t][dt] *= al;
            // pack P^T -> sPT[q][kr], one 8B half4 write per c-tile
#pragma unroll
            for (int c = 0; c < 4; c++) {
                half4v p = {(_Float16)sacc[t][c][0], (_Float16)sacc[t][c][1],
                            (_Float16)sacc[t][c][2], (_Float16)sacc[t][c][3]};
                *(half4v*)&sPT[wave][(t * 16 + l16) * 72 + c * 16 + quad * 4] = p;
            }
        }

        // PV: O^T += V^T P^T. A = V^T (m=d), B = P (n=q) from sPT.
#pragma unroll
        for (int kk = 0; kk < 2; kk++) {
            half8 pf0 = *(const half8*)&sPT[wave][(l16) * 72 + kk * 32 + quad * 8];
            half8 pf1 = *(const half8*)&sPT[wave][(16 + l16) * 72 + kk * 32 + quad * 8];
#pragma unroll
            for (int dt = 0; dt < 4; dt++) {
                half8 vf = *(const half8*)&sVT[(dt * 16 + l16) * 72 + kk * 32 + quad * 8];
                o[0][dt] = __builtin_amdgcn_mfma_f32_16x16x32_f16(vf, pf0, o[0][dt], 0, 0, 0);
                o[1][dt] = __builtin_amdgcn_mfma_f32_16x16x32_f16(vf, pf1, o[1][dt], 0, 0, 0);
            }
        }
    }

    // epilogue: normalize, per-wave LDS transpose (O^T -> O), coalesced 16B stores
#pragma unroll
    for (int t = 0; t < 2; t++) {
        float inv = 1.f / l_[t];
#pragma unroll
        for (int dt = 0; dt < 4; dt++) {
            floatx4 v = o[t][dt];
            half4v a = {(_Float16)(v[0] * inv), (_Float16)(v[1] * inv),
                        (_Float16)(v[2] * inv), (_Float16)(v[3] * inv)};
            *(half4v*)&sPT[wave][(t * 16 + l16) * 72 + dt * 16 + quad * 4] = a;
        }
    }
    __syncthreads();
#pragma unroll
    for (int i = 0; i < 4; i++) {
        int ql = i * 8 + (lane >> 3);
        int c8 = (lane & 7) * 8;
        half8 vv = *(const half8*)&sPT[wave][ql * 72 + c8];
        *(half8*)(out + (long)(b * 1024 + n0 + wave * 32 + ql) * 1024 + h * 64 + c8) = vv;
    }
}

// ---------------- launch ----------------
extern "C" void kernel_launch(void* const* d_in, const int* in_sizes, int n_in,
                              void* d_out, int out_size, void* d_ws, size_t ws_size,
                              hipStream_t stream) {
    const float* x      = (const float*)d_in[0];
    const float* w_qkv  = (const float*)d_in[1];
    const float* w_proj = (const float*)d_in[2];
    const float* b_proj = (const float*)d_in[3];

    char* ws = (char*)d_ws;
    _Float16* qkh    = (_Float16*)ws;                      // 32MB [8192][2048] (Q|K)
    _Float16* vT     = (_Float16*)(ws + 33554432);         // 16MB [128*64][1024] (V^T), by GEMM1
    _Float16* xh     = (_Float16*)(ws + 50331648);         // 16MB [8192][1024]; attnh alias
    _Float16* wqkvh  = (_Float16*)(ws + 67108864);         // 6MB [3072][1024]
    _Float16* wprojh = (_Float16*)(ws + 73400320);         // 2MB [1024][1024]
    _Float16* attnh  = xh;                                 // flash out (xh dead after GEMM1)

    cvt_all<<<12288, 256, 0, stream>>>(x, w_qkv, w_proj, xh, wqkvh, wprojh);

    // QKV GEMM: cols 0..2047 -> qkh row-major, cols 2048..3071 -> vT transposed
    gemm_tn<<<dim3(64, 24), 256, 0, stream>>>(xh, wqkvh, qkh, 2048, vT, 2048,
                                              nullptr, nullptr, 8192, 3072, 1024);
    flash_attn<<<dim3(128, 8), 256, 0, stream>>>(qkh, vT, attnh);
    gemm_tn<<<dim3(64, 8), 256, 0, stream>>>(attnh, wprojh, nullptr, 0, nullptr, 1 << 30,
                                             (float*)d_out, b_proj, 8192, 1024, 1024);
}

// Round 9
// 253.553 us; speedup vs baseline: 1.0330x; 1.0330x over previous
//
#include <hip/hip_runtime.h>

typedef _Float16 half8 __attribute__((ext_vector_type(8)));
typedef _Float16 half4v __attribute__((ext_vector_type(4)));
typedef float floatx4 __attribute__((ext_vector_type(4)));

#define AS3 __attribute__((address_space(3)))
#define AS1 __attribute__((address_space(1)))

// ---------------- fused f32 -> f16 convert of all three inputs ----------------
__global__ __launch_bounds__(256) void cvt_all(const float* __restrict__ x,
                                               const float* __restrict__ wq,
                                               const float* __restrict__ wp,
                                               _Float16* __restrict__ xh,
                                               _Float16* __restrict__ wqh,
                                               _Float16* __restrict__ wph) {
    long i = (long)blockIdx.x * 256 + threadIdx.x;   // float4 index
    const float4* src; half4v* dst; long off;
    if (i < 2097152)      { src = (const float4*)x;  dst = (half4v*)xh;  off = i; }
    else if (i < 2883584) { src = (const float4*)wq; dst = (half4v*)wqh; off = i - 2097152; }
    else                  { src = (const float4*)wp; dst = (half4v*)wph; off = i - 2883584; }
    float4 v = src[off];
    half4v h = {(_Float16)v.x, (_Float16)v.y, (_Float16)v.z, (_Float16)v.w};
    dst[off] = h;
}

// ---------------- TN GEMM, distance-2 global->VGPR->LDS pipeline -------------
// C[M,N] = A[M,K] * B[N,K]^T. 128x128 tile, BK=32, 256 threads, dbuf LDS.
// Two register staging sets in flight: loads for k-block kk+2 issue at iter
// kk; their vmcnt wait lands at iter kk+1's ds_write -- ~1 full iteration
// (>1000 cy) of latency cover vs distance-1's ~250 cy (R5/R7). Loop unrolled
// by 2 so set/buffer indices are compile-time. Requires nk even.
// Columns >= split are written TRANSPOSED into Vt[bh*64+d][n].
__global__ __launch_bounds__(256, 3) void gemm_tn(
    const _Float16* __restrict__ A, const _Float16* __restrict__ B,
    _Float16* __restrict__ Ch, int ldc, _Float16* __restrict__ Vt, int split,
    float* __restrict__ Cf, const float* __restrict__ bias,
    int M, int Nn, int K)
{
    __shared__ _Float16 sA[2][128 * 32];
    __shared__ _Float16 sB[2][128 * 32];
    const int tid  = threadIdx.x;
    const int lane = tid & 63, wave = tid >> 6;
    const int quad = lane >> 4, l16 = lane & 15;
    const int wr = wave >> 1, wc = wave & 1;
    const long m0 = (long)blockIdx.x * 128, n0 = (long)blockIdx.y * 128;

    // LDS placement: chunk c of row r -> slot c ^ ((r>>1)&3) (involution;
    // bank-uniform fragment reads, verified R3: SQ_LDS_BANK_CONFLICT = 0).
    const int srow = tid >> 2;
    const int sslot = ((tid & 3) ^ ((srow >> 1) & 3)) * 8;
    const int dlo = srow * 32 + sslot;
    const int dhi = (srow + 64) * 32 + sslot;
    const _Float16* gA0 = A + (m0 + srow) * (long)K + (tid & 3) * 8;
    const _Float16* gA1 = A + (m0 + srow + 64) * (long)K + (tid & 3) * 8;
    const _Float16* gB0 = B + (n0 + srow) * (long)K + (tid & 3) * 8;
    const _Float16* gB1 = B + (n0 + srow + 64) * (long)K + (tid & 3) * 8;

    const int swz = (l16 >> 1) & 3;
    const int aoff = ((quad ^ swz) * 8);

    floatx4 acc[4][4] = {};
    const int nk = K >> 5;   // even for K=1024

    // k-block 0 -> LDS buf 0 directly (vmcnt wait at the ds_write, once)
    {
        half8 a0 = *(const half8*)gA0, a1 = *(const half8*)gA1;
        half8 b0 = *(const half8*)gB0, b1 = *(const half8*)gB1;
        *(half8*)&sA[0][dlo] = a0; *(half8*)&sA[0][dhi] = a1;
        *(half8*)&sB[0][dlo] = b0; *(half8*)&sB[0][dhi] = b1;
    }
    // staging sets: at entry to iter k (parity u=k&1), set[u] holds block k+1
    half8 pA0[2], pA1[2], pB0[2], pB1[2];
    pA0[0] = *(const half8*)(gA0 + 32); pA1[0] = *(const half8*)(gA1 + 32);
    pB0[0] = *(const half8*)(gB0 + 32); pB1[0] = *(const half8*)(gB1 + 32);

    for (int kk = 0; kk < nk; kk += 2) {
#pragma unroll
        for (int u = 0; u < 2; u++) {
            const int k = kk + u;
            __syncthreads();   // buf[u^1] readers done; vmcnt for set[u] already waited last iter
            if (k + 2 < nk) {
                const long ko = (long)(k + 2) << 5;
                pA0[u ^ 1] = *(const half8*)(gA0 + ko);
                pA1[u ^ 1] = *(const half8*)(gA1 + ko);
                pB0[u ^ 1] = *(const half8*)(gB0 + ko);
                pB1[u ^ 1] = *(const half8*)(gB1 + ko);
            }

            const _Float16* cA = &sA[u][0];
            const _Float16* cB = &sB[u][0];
            half8 af[4], bf[4];
#pragma unroll
            for (int t = 0; t < 4; t++)
                af[t] = *(const half8*)&cA[(wr * 64 + t * 16 + l16) * 32 + aoff];
#pragma unroll
            for (int t = 0; t < 4; t++)
                bf[t] = *(const half8*)&cB[(wc * 64 + t * 16 + l16) * 32 + aoff];
#pragma unroll
            for (int tm = 0; tm < 4; tm++)
#pragma unroll
                for (int tn = 0; tn < 4; tn++)
                    acc[tm][tn] = __builtin_amdgcn_mfma_f32_16x16x32_f16(af[tm], bf[tn], acc[tm][tn], 0, 0, 0);

            if (k + 1 < nk) {
                _Float16* nA = &sA[u ^ 1][0];
                _Float16* nB = &sB[u ^ 1][0];
                *(half8*)&nA[dlo] = pA0[u];   // vmcnt wait: set[u] was issued one
                *(half8*)&nA[dhi] = pA1[u];   // full iteration ago
                *(half8*)&nB[dlo] = pB0[u];
                *(half8*)&nB[dhi] = pB1[u];
            }
        }
    }

    // epilogue: C/D layout col=lane&15, row=quad*4+reg (verified m89/m91)
#pragma unroll
    for (int tm = 0; tm < 4; tm++) {
        long row = m0 + wr * 64 + tm * 16 + quad * 4;
#pragma unroll
        for (int tn = 0; tn < 4; tn++) {
            long col = n0 + wc * 64 + tn * 16 + l16;
            if (Cf) {
                float bv = bias ? bias[col] : 0.f;
#pragma unroll
                for (int r = 0; r < 4; r++)
                    Cf[(row + r) * (long)Nn + col] = acc[tm][tn][r] + bv;
            } else if (col >= split) {
                long cv = col - split;
                long vrow = ((row >> 10) * 16 + (cv >> 6)) * 64 + (cv & 63);
                long nn = row & 1023;
                half4v pv = {(_Float16)acc[tm][tn][0], (_Float16)acc[tm][tn][1],
                             (_Float16)acc[tm][tn][2], (_Float16)acc[tm][tn][3]};
                *(half4v*)&Vt[vrow * 1024 + nn] = pv;
            } else {
#pragma unroll
                for (int r = 0; r < 4; r++)
                    Ch[(row + r) * (long)ldc + col] = (_Float16)acc[tm][tn][r];
            }
        }
    }
}

// ---------------- flash attention (S^T orientation, log2-domain softmax) -----
// R7 structure (direct load->ds_write staging, 4 waves/SIMD -- R8's 3-wave
// prefetch variant regressed: occupancy buys more than distance-1 ILP here).
// Q fragments pre-scaled by 0.125*log2(e); softmax in log2 domain via exp2f.
#define QSC 0.18033688f
__global__ __launch_bounds__(256, 4) void flash_attn(const _Float16* __restrict__ qk,
                                                     const _Float16* __restrict__ vt,
                                                     _Float16* __restrict__ out)
{
    const int bh = blockIdx.x, b = bh >> 4, h = bh & 15;
    const int n0 = blockIdx.y * 128;
    const int tid = threadIdx.x, lane = tid & 63, wave = tid >> 6;
    const int quad = lane >> 4, l16 = lane & 15;

    __shared__ _Float16 sK[64 * 72];        // [kr][d] pad 72
    __shared__ _Float16 sVT[64 * 72];       // [d][kr] pad 72
    __shared__ _Float16 sPT[4][32 * 72];    // per-wave P^T round-trip [q][kr], reused as sOut

    half8 qf[2][2];
    const _Float16 qs = (_Float16)QSC;
    const _Float16* qbase = qk + (long)(b * 1024 + n0 + wave * 32) * 2048 + h * 64;
#pragma unroll
    for (int t = 0; t < 2; t++)
#pragma unroll
        for (int s = 0; s < 2; s++) {
            half8 v = *(const half8*)(qbase + (long)(t * 16 + l16) * 2048 + s * 32 + quad * 8);
#pragma unroll
            for (int j = 0; j < 8; j++) v[j] *= qs;
            qf[t][s] = v;
        }

    const int srow = tid >> 3, scol8 = (tid & 7) * 8;
    const _Float16* kgb = qk + 1024 + h * 64 + scol8 + (long)(b * 1024 + srow) * 2048;
    const _Float16* vgb = vt + (long)(bh * 64 + srow) * 1024 + scol8;

    float m_[2] = {-1e30f, -1e30f}, l_[2] = {0.f, 0.f};
    floatx4 o[2][4] = {};

    for (int kt = 0; kt < 16; kt++) {
        const int kr0 = kt * 64;
        __syncthreads();
#pragma unroll
        for (int i = 0; i < 2; i++) {
            int r = srow + i * 32;
            *(half8*)&sK[r * 72 + scol8]  = *(const half8*)(kgb + (long)(kr0 + i * 32) * 2048);
            *(half8*)&sVT[r * 72 + scol8] = *(const half8*)(vgb + (long)(i * 32) * 1024 + kr0);
        }
        __syncthreads();

        // S^T = K Q^T (log2-domain): kr=c*16+quad*4+r, q=t*16+l16
        floatx4 sacc[2][4] = {};
#pragma unroll
        for (int c = 0; c < 4; c++)
#pragma unroll
            for (int s = 0; s < 2; s++) {
                half8 kf = *(const half8*)&sK[(c * 16 + l16) * 72 + s * 32 + quad * 8];
                sacc[0][c] = __builtin_amdgcn_mfma_f32_16x16x32_f16(kf, qf[0][s], sacc[0][c], 0, 0, 0);
                sacc[1][c] = __builtin_amdgcn_mfma_f32_16x16x32_f16(kf, qf[1][s], sacc[1][c], 0, 0, 0);
            }

        // online softmax over kr (log2 domain): in-lane reduce + xor16/xor32
#pragma unroll
        for (int t = 0; t < 2; t++) {
            float mx = -1e30f;
#pragma unroll
            for (int c = 0; c < 4; c++)
#pragma unroll
                for (int r = 0; r < 4; r++) mx = fmaxf(mx, sacc[t][c][r]);
            mx = fmaxf(mx, __shfl_xor(mx, 16));
            mx = fmaxf(mx, __shfl_xor(mx, 32));
            float mn = fmaxf(m_[t], mx);
            float al = exp2f(m_[t] - mn);
            m_[t] = mn;
            float rs = 0.f;
#pragma unroll
            for (int c = 0; c < 4; c++)
#pragma unroll
                for (int r = 0; r < 4; r++) {
                    float p = exp2f(sacc[t][c][r] - mn);
                    sacc[t][c][r] = p;
                    rs += p;
                }
            rs += __shfl_xor(rs, 16);
            rs += __shfl_xor(rs, 32);
            l_[t] = l_[t] * al + rs;
#pragma unroll
            for (int dt = 0; dt < 4; dt++) o[t][dt] *= al;
            // pack P^T -> sPT[q][kr], one 8B half4 write per c-tile
#pragma unroll
            for (int c = 0; c < 4; c++) {
                half4v p = {(_Float16)sacc[t][c][0], (_Float16)sacc[t][c][1],
                            (_Float16)sacc[t][c][2], (_Float16)sacc[t][c][3]};
                *(half4v*)&sPT[wave][(t * 16 + l16) * 72 + c * 16 + quad * 4] = p;
            }
        }

        // PV: O^T += V^T P^T. A = V^T (m=d), B = P (n=q) from sPT.
#pragma unroll
        for (int kk = 0; kk < 2; kk++) {
            half8 pf0 = *(const half8*)&sPT[wave][(l16) * 72 + kk * 32 + quad * 8];
            half8 pf1 = *(const half8*)&sPT[wave][(16 + l16) * 72 + kk * 32 + quad * 8];
#pragma unroll
            for (int dt = 0; dt < 4; dt++) {
                half8 vf = *(const half8*)&sVT[(dt * 16 + l16) * 72 + kk * 32 + quad * 8];
                o[0][dt] = __builtin_amdgcn_mfma_f32_16x16x32_f16(vf, pf0, o[0][dt], 0, 0, 0);
                o[1][dt] = __builtin_amdgcn_mfma_f32_16x16x32_f16(vf, pf1, o[1][dt], 0, 0, 0);
            }
        }
    }

    // epilogue: normalize, per-wave LDS transpose (O^T -> O), coalesced 16B stores
#pragma unroll
    for (int t = 0; t < 2; t++) {
        float inv = 1.f / l_[t];
#pragma unroll
        for (int dt = 0; dt < 4; dt++) {
            floatx4 v = o[t][dt];
            half4v a = {(_Float16)(v[0] * inv), (_Float16)(v[1] * inv),
                        (_Float16)(v[2] * inv), (_Float16)(v[3] * inv)};
            *(half4v*)&sPT[wave][(t * 16 + l16) * 72 + dt * 16 + quad * 4] = a;
        }
    }
    __syncthreads();
#pragma unroll
    for (int i = 0; i < 4; i++) {
        int ql = i * 8 + (lane >> 3);
        int c8 = (lane & 7) * 8;
        half8 vv = *(const half8*)&sPT[wave][ql * 72 + c8];
        *(half8*)(out + (long)(b * 1024 + n0 + wave * 32 + ql) * 1024 + h * 64 + c8) = vv;
    }
}

// ---------------- launch ----------------
extern "C" void kernel_launch(void* const* d_in, const int* in_sizes, int n_in,
                              void* d_out, int out_size, void* d_ws, size_t ws_size,
                              hipStream_t stream) {
    const float* x      = (const float*)d_in[0];
    const float* w_qkv  = (const float*)d_in[1];
    const float* w_proj = (const float*)d_in[2];
    const float* b_proj = (const float*)d_in[3];

    char* ws = (char*)d_ws;
    _Float16* qkh    = (_Float16*)ws;                      // 32MB [8192][2048] (Q|K)
    _Float16* vT     = (_Float16*)(ws + 33554432);         // 16MB [128*64][1024] (V^T), by GEMM1
    _Float16* xh     = (_Float16*)(ws + 50331648);         // 16MB [8192][1024]; attnh alias
    _Float16* wqkvh  = (_Float16*)(ws + 67108864);         // 6MB [3072][1024]
    _Float16* wprojh = (_Float16*)(ws + 73400320);         // 2MB [1024][1024]
    _Float16* attnh  = xh;                                 // flash out (xh dead after GEMM1)

    cvt_all<<<12288, 256, 0, stream>>>(x, w_qkv, w_proj, xh, wqkvh, wprojh);

    // QKV GEMM: cols 0..2047 -> qkh row-major, cols 2048..3071 -> vT transposed
    gemm_tn<<<dim3(64, 24), 256, 0, stream>>>(xh, wqkvh, qkh, 2048, vT, 2048,
                                              nullptr, nullptr, 8192, 3072, 1024);
    flash_attn<<<dim3(128, 8), 256, 0, stream>>>(qkh, vT, attnh);
    gemm_tn<<<dim3(64, 8), 256, 0, stream>>>(attnh, wprojh, nullptr, 0, nullptr, 1 << 30,
                                             (float*)d_out, b_proj, 8192, 1024, 1024);
}